// Round 5
// baseline (302.631 us; speedup 1.0000x reference)
//
#include <hip/hip_runtime.h>
#include <cstdint>
#include <cstddef>

typedef __bf16 bf16x8 __attribute__((ext_vector_type(8)));
typedef __bf16 bf16x4 __attribute__((ext_vector_type(4)));
typedef float  f32x4  __attribute__((ext_vector_type(4)));

#define MFMA16(a, b, c) __builtin_amdgcn_mfma_f32_16x16x32_bf16((a), (b), (c), 0, 0, 0)

// async global->LDS, 16B per lane. LDS dest MUST be wave_base + lane*16 (contiguous).
#define GLL16(gsrc, ldst)                                                              \
  __builtin_amdgcn_global_load_lds((__attribute__((address_space(1))) void*)(gsrc),    \
                                   (__attribute__((address_space(3))) void*)(ldst),    \
                                   16, 0, 0)

// q pre-scale: 1/sqrt(64) * log2(e), so attention scores land in log2 space
#define QSCALE 0.1803368801111204f

// ---------------------------------------------------------------- conversions

__global__ __launch_bounds__(256)
void cvt_f32_bf16(const float* __restrict__ in, __bf16* __restrict__ out, int n4)
{
    int i = blockIdx.x * 256 + threadIdx.x;
    if (i < n4) {
        float4 v = ((const float4*)in)[i];
        bf16x4 o;
        o[0] = (__bf16)v.x; o[1] = (__bf16)v.y; o[2] = (__bf16)v.z; o[3] = (__bf16)v.w;
        ((bf16x4*)out)[i] = o;
    }
}

// in: fp32 [K][N] row-major -> out: bf16 [N][K] row-major
__global__ __launch_bounds__(256)
void transpose_cvt(const float* __restrict__ in, __bf16* __restrict__ out, int K, int N)
{
    __shared__ __bf16 tile[32][33];
    const int n0 = blockIdx.x * 32, k0 = blockIdx.y * 32;
    const int tx = threadIdx.x, ty = threadIdx.y;
    #pragma unroll
    for (int i = 0; i < 4; ++i)
        tile[ty + i * 8][tx] = (__bf16)in[(size_t)(k0 + ty + i * 8) * N + n0 + tx];
    __syncthreads();
    #pragma unroll
    for (int i = 0; i < 4; ++i)
        out[(size_t)(n0 + ty + i * 8) * K + k0 + tx] = tile[tx][ty + i * 8];
}

// ---------------------------------------------------------------- QKV GEMM
// 128x128 tile + T1 XCD-chunked remap (FETCH 71.8 -> 41.4 MB measured, r4).
// NEW (r5): for sec==2 (V) blocks, the vtrans kernel is folded into the
// epilogue: the block owns a full 128t x (2 heads x 64d) V tile, so it writes
// vout fp32 (required output) AND stages bf16 into a padded LDS buffer,
// transposes, and writes vwst [bh][d][t] with the sigma permutation
// (position p holds t_local = 16*(p&3)+(p>>2), i.e. p(tau) = 4*(tau&15)+(tau>>4))
// directly. Saves the separate 32MB-read/16MB-write vtrans dispatch.

union SmemQKV {
    struct { __bf16 As[128 * 32]; __bf16 Bs[128 * 32]; } g;   // 16 KB
    __bf16 VtL[2][64][136];                                   // 34 KB, 136 pad:
};                                                            // 16B-aligned rows

__global__ __launch_bounds__(256)
void gemm_qkv(const __bf16* __restrict__ A, const __bf16* __restrict__ Bt,
              const float* __restrict__ bias,
              __bf16* __restrict__ qws, float* __restrict__ kout, float* __restrict__ vout,
              __bf16* __restrict__ kws, __bf16* __restrict__ vwst)
{
    constexpr int K = 1024;
    // XCD-chunked bijective remap (1536 blocks, 1536 % 8 == 0)
    const int d   = blockIdx.y * 24 + blockIdx.x;   // HW dispatch order (x fastest)
    const int xcd = d & 7, loc = d >> 3;            // XCD = d % 8
    const int m0 = (xcd * 8 + (loc & 7)) * 128;     // 8 m-tiles per XCD, hot in L2
    const int n0 = (loc >> 3) * 128;                // n-major sweep within XCD
    const int tid = threadIdx.x;
    const int wave = tid >> 6, lane = tid & 63;
    const int quad = lane >> 4, lr = lane & 15;
    const int wrow = (wave & 1) * 64, wcol = (wave >> 1) * 64;

    __shared__ SmemQKV sm;

    f32x4 acc[4][4];
    #pragma unroll
    for (int mi = 0; mi < 4; ++mi)
      #pragma unroll
      for (int ni = 0; ni < 4; ++ni)
        #pragma unroll
        for (int c = 0; c < 4; ++c) acc[mi][ni][c] = 0.f;

    const int u0 = tid, u1 = tid + 256;
    const int cg0 = ((u0 & 3) ^ ((u0 >> 3) & 3)) * 8;
    const int cg1 = ((u1 & 3) ^ ((u1 >> 3) & 3)) * 8;
    const __bf16* ga0 = A  + (size_t)(m0 + (u0 >> 2)) * K + cg0;
    const __bf16* ga1 = A  + (size_t)(m0 + (u1 >> 2)) * K + cg1;
    const __bf16* gb0 = Bt + (size_t)(n0 + (u0 >> 2)) * K + cg0;
    const __bf16* gb1 = Bt + (size_t)(n0 + (u1 >> 2)) * K + cg1;
    __bf16* la0 = sm.g.As + u0 * 8;
    __bf16* la1 = sm.g.As + u1 * 8;
    __bf16* lb0 = sm.g.Bs + u0 * 8;
    __bf16* lb1 = sm.g.Bs + u1 * 8;

    const int sw = (quad ^ ((lr >> 1) & 3)) * 8;

    for (int kt = 0; kt < K; kt += 32) {
        __syncthreads();
        GLL16(ga0 + kt, la0);
        GLL16(ga1 + kt, la1);
        GLL16(gb0 + kt, lb0);
        GLL16(gb1 + kt, lb1);
        __syncthreads();
        bf16x8 af[4], bfv[4];
        #pragma unroll
        for (int mi = 0; mi < 4; ++mi)
            af[mi] = *(const bf16x8*)&sm.g.As[(wrow + mi * 16 + lr) * 32 + sw];
        #pragma unroll
        for (int ni = 0; ni < 4; ++ni)
            bfv[ni] = *(const bf16x8*)&sm.g.Bs[(wcol + ni * 16 + lr) * 32 + sw];
        #pragma unroll
        for (int mi = 0; mi < 4; ++mi)
          #pragma unroll
          for (int ni = 0; ni < 4; ++ni)
            acc[mi][ni] = MFMA16(af[mi], bfv[ni], acc[mi][ni]);
    }

    const int sec = n0 >> 10;  // 0=q, 1=k, 2=v (block-uniform: 128 | 1024)

    if (sec == 2) {
        // drain all waves' last LDS frag reads before reusing smem as VtL
        __syncthreads();
    }

    #pragma unroll
    for (int ni = 0; ni < 4; ++ni) {
        const int gn = n0 + wcol + ni * 16 + lr;
        const float bv = bias[gn];
        const int cn = gn & 1023, hh = cn >> 6, dd = cn & 63;
        #pragma unroll
        for (int mi = 0; mi < 4; ++mi) {
            const int gm0 = m0 + wrow + mi * 16 + quad * 4;
            const int b = gm0 >> 11, t0 = gm0 & 2047;
            const size_t tb = ((size_t)b * 16 + hh) * 2048;
            if (sec == 0) {
                #pragma unroll
                for (int r = 0; r < 4; ++r)
                    qws[(tb + t0 + r) * 64 + dd] = (__bf16)((acc[mi][ni][r] + bv) * QSCALE);
            } else if (sec == 1) {
                #pragma unroll
                for (int r = 0; r < 4; ++r) {
                    const float val = acc[mi][ni][r] + bv;
                    kout[(tb + t0 + r) * 64 + dd] = val;
                    kws [(tb + t0 + r) * 64 + dd] = (__bf16)val;
                }
            } else {
                #pragma unroll
                for (int r = 0; r < 4; ++r) {
                    const float val = acc[mi][ni][r] + bv;
                    vout[(tb + t0 + r) * 64 + dd] = val;
                    // sigma-permuted LDS stage for the fused V transpose
                    const int tau = wrow + mi * 16 + quad * 4 + r;     // 0..127
                    const int t64 = tau & 63, blk = tau >> 6;
                    const int p = 4 * (t64 & 15) + (t64 >> 4);
                    sm.VtL[hh & 1][dd][blk * 64 + p] = (__bf16)val;
                }
            }
        }
    }

    if (sec == 2) {
        __syncthreads();
        // write-out: vwst [bh][d][2048], rows of 128 t contiguous
        const int b = m0 >> 11, t_base = m0 & 2047;
        const int hh0 = (n0 & 1023) >> 6;          // even head index of this block
        #pragma unroll
        for (int k = 0; k < 8; ++k) {
            const int e  = (tid + 256 * k) * 8;    // element index
            const int p8 = e & 127;
            const int dd = (e >> 7) & 63;
            const int hl = e >> 13;                // local head 0/1
            bf16x8 v = *(const bf16x8*)&sm.VtL[hl][dd][p8];
            const int bh = b * 16 + hh0 + hl;
            *(bf16x8*)&vwst[((size_t)bh * 64 + dd) * 2048 + t_base + p8] = v;
        }
    }
}

// ---------------------------------------------------------------- out-proj GEMM
// r5: 128x128 tile (gemm_qkv structure, 4x4 acc/wave), grid (8,64) = 512 blocks.
// XCD affinity natural: dispatch d = x + 8y, d%8 = x = n-tile, so each XCD
// keeps one 128-col B panel (256 KB) L2-hot and streams A once.

__global__ __launch_bounds__(256)
void gemm_out(const __bf16* __restrict__ A, const __bf16* __restrict__ Bt,
              const float* __restrict__ bias, float* __restrict__ y)
{
    constexpr int K = 1024;
    const int m0 = blockIdx.y * 128, n0 = blockIdx.x * 128;
    const int tid = threadIdx.x;
    const int wave = tid >> 6, lane = tid & 63;
    const int quad = lane >> 4, lr = lane & 15;
    const int wrow = (wave & 1) * 64, wcol = (wave >> 1) * 64;

    __shared__ __bf16 As[128 * 32];
    __shared__ __bf16 Bs[128 * 32];

    f32x4 acc[4][4];
    #pragma unroll
    for (int mi = 0; mi < 4; ++mi)
      #pragma unroll
      for (int ni = 0; ni < 4; ++ni)
        #pragma unroll
        for (int c = 0; c < 4; ++c) acc[mi][ni][c] = 0.f;

    const int u0 = tid, u1 = tid + 256;
    const int cg0 = ((u0 & 3) ^ ((u0 >> 3) & 3)) * 8;
    const int cg1 = ((u1 & 3) ^ ((u1 >> 3) & 3)) * 8;
    const __bf16* ga0 = A  + (size_t)(m0 + (u0 >> 2)) * K + cg0;
    const __bf16* ga1 = A  + (size_t)(m0 + (u1 >> 2)) * K + cg1;
    const __bf16* gb0 = Bt + (size_t)(n0 + (u0 >> 2)) * K + cg0;
    const __bf16* gb1 = Bt + (size_t)(n0 + (u1 >> 2)) * K + cg1;
    __bf16* la0 = As + u0 * 8;
    __bf16* la1 = As + u1 * 8;
    __bf16* lb0 = Bs + u0 * 8;
    __bf16* lb1 = Bs + u1 * 8;

    const int sw = (quad ^ ((lr >> 1) & 3)) * 8;

    for (int kt = 0; kt < K; kt += 32) {
        __syncthreads();
        GLL16(ga0 + kt, la0);
        GLL16(ga1 + kt, la1);
        GLL16(gb0 + kt, lb0);
        GLL16(gb1 + kt, lb1);
        __syncthreads();
        bf16x8 af[4], bfv[4];
        #pragma unroll
        for (int mi = 0; mi < 4; ++mi)
            af[mi] = *(const bf16x8*)&As[(wrow + mi * 16 + lr) * 32 + sw];
        #pragma unroll
        for (int ni = 0; ni < 4; ++ni)
            bfv[ni] = *(const bf16x8*)&Bs[(wcol + ni * 16 + lr) * 32 + sw];
        #pragma unroll
        for (int mi = 0; mi < 4; ++mi)
          #pragma unroll
          for (int ni = 0; ni < 4; ++ni)
            acc[mi][ni] = MFMA16(af[mi], bfv[ni], acc[mi][ni]);
    }

    #pragma unroll
    for (int ni = 0; ni < 4; ++ni) {
        const int gn = n0 + wcol + ni * 16 + lr;
        const float bv = bias[gn];
        #pragma unroll
        for (int mi = 0; mi < 4; ++mi) {
            #pragma unroll
            for (int r = 0; r < 4; ++r) {
                const int gm = m0 + wrow + mi * 16 + quad * 4 + r;
                y[(size_t)gm * 1024 + gn] = acc[mi][ni][r] + bv;
            }
        }
    }
}

// ---------------------------------------------------------------- flash attention
// Grid (bh, pair): all 8 pair-blocks of a bh land on one XCD (linear id % 8 = bh % 8).
// Two serialized phases (q-tiles {x,15-x}), 34 tile-iters per block. Fixed-shift
// softmax: sacc init = -12, p = exp2(s-12), exact after final 1/l (no running max).
// 3-buffer KV, 2-deep prefetch, ONE barrier per iter (prefetch targets buf+2).
// r5: s_setprio(1) around MFMA packs (T5: measured +4-7% on attn, m191).

__global__ __launch_bounds__(256, 2)
void attn_fused(const __bf16* __restrict__ qws, const __bf16* __restrict__ kws,
                const __bf16* __restrict__ vwst, __bf16* __restrict__ attnws)
{
    const int bh = blockIdx.x;          // b*16 + h
    const int tid = threadIdx.x;
    const int wave = tid >> 6, lane = tid & 63;
    const int quad = lane >> 4, lr = lane & 15;

    const int jqp[2] = { (int)blockIdx.y, 15 - (int)blockIdx.y };
    const int ntp[2] = { 2 * (jqp[0] + 1), 2 * (jqp[1] + 1) };
    const int nt0 = ntp[0];
    const int ntot = 34;

    __shared__ __bf16 Ks [3][2][64][32];   // [buf][s][kv][d32]   swizzled cols
    __shared__ __bf16 Vts[3][2][64][32];   // [buf][s][d][p32]    swizzled cols
    __shared__ __bf16 Ps [4][32][72];      // per-wave P, c_store = 4*lr+ni order

    // staging addresses
    const int srow = tid >> 2;
    const int scg  = ((tid & 3) ^ ((tid >> 3) & 3)) * 8;
    const __bf16* kb = kws  + ((size_t)bh * 2048 + srow) * 64 + scg;
    const __bf16* vb = vwst + ((size_t)bh * 64 + srow) * 2048 + scg;
    char* lk = (char*)Ks  + tid * 16;   // + buf*8192 (+4096 for s1)
    char* lv = (char*)Vts + tid * 16;

    const int sw = (quad ^ ((lr >> 1) & 3)) * 8;

    bf16x8 ones;
    #pragma unroll
    for (int j = 0; j < 8; ++j) ones[j] = (__bf16)1.0f;

    // Q fragments for BOTH phases up-front (keeps vmcnt FIFO discipline clean)
    bf16x8 aq[2][2][2];
    #pragma unroll
    for (int h = 0; h < 2; ++h)
      #pragma unroll
      for (int mi = 0; mi < 2; ++mi) {
        const __bf16* qb = qws + ((size_t)bh * 2048 + jqp[h] * 128 + wave * 32 + mi * 16 + lr) * 64 + quad * 8;
        aq[h][mi][0] = *(const bf16x8*)qb;
        aq[h][mi][1] = *(const bf16x8*)(qb + 32);
      }

#define PREFETCH(j, buf)                                                \
    do {                                                                \
        GLL16(kb + (size_t)(j) * 4096,      lk + (buf) * 8192);         \
        GLL16(kb + (size_t)(j) * 4096 + 32, lk + (buf) * 8192 + 4096);  \
        GLL16(vb + (j) * 64,                lv + (buf) * 8192);         \
        GLL16(vb + (j) * 64 + 32,           lv + (buf) * 8192 + 4096);  \
    } while (0)

    // prologue: tiles 0 and 1 (phase-0 always has >= 2 tiles)
    PREFETCH(0, 0);
    PREFETCH(1, 1);

    bf16x4 oreg[2][2][4];   // [h][mi][n], r packed in vector lanes

    int pos = 0;
    for (int h = 0; h < 2; ++h) {
        const int jq = jqp[h];
        const int NT = ntp[h];

        f32x4 o_acc[2][4], l_acc[2];
        #pragma unroll
        for (int mi = 0; mi < 2; ++mi) {
            #pragma unroll
            for (int r = 0; r < 4; ++r) l_acc[mi][r] = 0.f;
            #pragma unroll
            for (int n = 0; n < 4; ++n)
                #pragma unroll
                for (int r = 0; r < 4; ++r) o_acc[mi][n][r] = 0.f;
        }

        for (int jt = 0; jt < NT; ++jt, ++pos) {
            const int cur = pos % 3;
            // tile `pos` was requested 2 iters ago; tile pos+1 is 1 deep in flight
            if (pos + 1 < ntot) {
                asm volatile("s_waitcnt vmcnt(4)" ::: "memory");
            } else {
                asm volatile("s_waitcnt vmcnt(0)" ::: "memory");
            }
            asm volatile("s_waitcnt lgkmcnt(0)" ::: "memory");
            asm volatile("s_barrier" ::: "memory");
            if (pos + 2 < ntot) {
                const int p2 = pos + 2;
                const int nj = (p2 < nt0) ? p2 : p2 - nt0;
                PREFETCH(nj, p2 % 3);
            }

            const bool lastTile = (jt == NT - 1);
            if (!(lastTile && wave < 2)) {
                // S = Q K^T, C initialized to -12 (fixed softmax shift, free)
                bf16x8 bk[4][2];
                #pragma unroll
                for (int ni = 0; ni < 4; ++ni) {
                    bk[ni][0] = *(const bf16x8*)&Ks[cur][0][ni * 16 + lr][sw];
                    bk[ni][1] = *(const bf16x8*)&Ks[cur][1][ni * 16 + lr][sw];
                }
                f32x4 sacc[2][4];
                #pragma unroll
                for (int mi = 0; mi < 2; ++mi)
                  #pragma unroll
                  for (int ni = 0; ni < 4; ++ni)
                    #pragma unroll
                    for (int c = 0; c < 4; ++c) sacc[mi][ni][c] = -12.f;
                __builtin_amdgcn_s_setprio(1);
                #pragma unroll
                for (int ni = 0; ni < 4; ++ni)
                  #pragma unroll
                  for (int mi = 0; mi < 2; ++mi) {
                    sacc[mi][ni] = MFMA16(aq[h][mi][0], bk[ni][0], sacc[mi][ni]);
                    sacc[mi][ni] = MFMA16(aq[h][mi][1], bk[ni][1], sacc[mi][ni]);
                  }
                __builtin_amdgcn_s_setprio(0);

                // causal mask: only waves whose rows straddle this tile
                const bool needMask = (jt == NT - 2 && wave < 2) || (lastTile && wave >= 2);
                if (needMask) {
                    const int c0 = jt * 64 + lr;
                    #pragma unroll
                    for (int mi = 0; mi < 2; ++mi) {
                        const int t0 = jq * 128 + wave * 32 + mi * 16 + quad * 4;
                        #pragma unroll
                        for (int ni = 0; ni < 4; ++ni)
                          #pragma unroll
                          for (int r = 0; r < 4; ++r)
                            if (c0 + ni * 16 > t0 + r) sacc[mi][ni][r] = -1e30f;
                    }
                }

                // p = exp2(s - 12); packed b64 store (no max, no alpha)
                #pragma unroll
                for (int mi = 0; mi < 2; ++mi)
                  #pragma unroll
                  for (int r = 0; r < 4; ++r) {
                    bf16x4 pp;
                    #pragma unroll
                    for (int ni = 0; ni < 4; ++ni)
                        pp[ni] = (__bf16)__builtin_amdgcn_exp2f(sacc[mi][ni][r]);
                    *(bf16x4*)&Ps[wave][mi * 16 + quad * 4 + r][4 * lr] = pp;
                  }

                // Ps is wave-private: drain own LDS writes, no barrier
                asm volatile("s_waitcnt lgkmcnt(0)" ::: "memory");

                // O += P V ; l += P . 1   (V rows sigma-permuted to match P)
                bf16x8 bv[4][2];
                #pragma unroll
                for (int n = 0; n < 4; ++n) {
                    bv[n][0] = *(const bf16x8*)&Vts[cur][0][n * 16 + lr][sw];
                    bv[n][1] = *(const bf16x8*)&Vts[cur][1][n * 16 + lr][sw];
                }
                __builtin_amdgcn_s_setprio(1);
                #pragma unroll
                for (int mi = 0; mi < 2; ++mi) {
                    bf16x8 ap0 = *(const bf16x8*)&Ps[wave][mi * 16 + lr][quad * 8];
                    bf16x8 ap1 = *(const bf16x8*)&Ps[wave][mi * 16 + lr][32 + quad * 8];
                    l_acc[mi] = MFMA16(ap0, ones, l_acc[mi]);
                    l_acc[mi] = MFMA16(ap1, ones, l_acc[mi]);
                    #pragma unroll
                    for (int n = 0; n < 4; ++n) {
                        o_acc[mi][n] = MFMA16(ap0, bv[n][0], o_acc[mi][n]);
                        o_acc[mi][n] = MFMA16(ap1, bv[n][1], o_acc[mi][n]);
                    }
                }
                __builtin_amdgcn_s_setprio(0);
            }
        }

        // normalize into registers (stores deferred to kernel end)
        #pragma unroll
        for (int mi = 0; mi < 2; ++mi)
          #pragma unroll
          for (int r = 0; r < 4; ++r) {
            const float inv = 1.f / l_acc[mi][r];
            #pragma unroll
            for (int n = 0; n < 4; ++n)
                oreg[h][mi][n][r] = (__bf16)(o_acc[mi][n][r] * inv);
          }
    }

    // epilogue: store both phases (bf16, [B,T,NH*HD] for the out-proj GEMM)
    const int b = bh >> 4, h16 = bh & 15;
    #pragma unroll
    for (int h = 0; h < 2; ++h)
      #pragma unroll
      for (int mi = 0; mi < 2; ++mi)
        #pragma unroll
        for (int r = 0; r < 4; ++r) {
            const int t = jqp[h] * 128 + wave * 32 + mi * 16 + quad * 4 + r;
            #pragma unroll
            for (int n = 0; n < 4; ++n)
                attnws[(((size_t)b * 2048 + t) * 16 + h16) * 64 + n * 16 + lr] =
                    oreg[h][mi][n][r];
        }
#undef PREFETCH
}

// ---------------------------------------------------------------- launcher

extern "C" void kernel_launch(void* const* d_in, const int* in_sizes, int n_in,
                              void* d_out, int out_size, void* d_ws, size_t ws_size,
                              hipStream_t stream)
{
    (void)in_sizes; (void)n_in; (void)out_size; (void)ws_size;

    const float* x    = (const float*)d_in[0];
    const float* Wqkv = (const float*)d_in[1];
    const float* bqkv = (const float*)d_in[2];
    const float* Wout = (const float*)d_in[3];
    const float* bout = (const float*)d_in[4];

    float* y    = (float*)d_out;          // [4,2048,1024]
    float* kout = y + 8388608;            // [4,16,2048,64]
    float* vout = kout + 8388608;         // [4,16,2048,64]

    char* ws = (char*)d_ws;
    __bf16* xb    = (__bf16*)(ws);                       // 16 MB  [8192,1024]
    __bf16* wqkvt = (__bf16*)(ws + (16u << 20));         //  6 MB  [3072,1024]
    __bf16* woutt = (__bf16*)(ws + (22u << 20));         //  2 MB  [1024,1024]
    __bf16* qws   = (__bf16*)(ws + (24u << 20));         // 16 MB  [64,2048,64]  (pre-scaled)
    __bf16* kws   = (__bf16*)(ws + (40u << 20));         // 16 MB  [64,2048,64]
    __bf16* vwst  = (__bf16*)(ws + (56u << 20));         // 16 MB  [64,64,2048]  (sigma-permuted)
    __bf16* attnw = (__bf16*)(ws + (72u << 20));         // 16 MB  [8192,1024]

    cvt_f32_bf16<<<8192, 256, 0, stream>>>(x, xb, 2097152);
    transpose_cvt<<<dim3(96, 32), dim3(32, 8), 0, stream>>>(Wqkv, wqkvt, 1024, 3072);
    transpose_cvt<<<dim3(32, 32), dim3(32, 8), 0, stream>>>(Wout, woutt, 1024, 1024);
    gemm_qkv<<<dim3(24, 64), 256, 0, stream>>>(xb, wqkvt, bqkv, qws, kout, vout, kws, vwst);
    attn_fused<<<dim3(64, 8), 256, 0, stream>>>(qws, kws, vwst, attnw);
    gemm_out<<<dim3(8, 64), 256, 0, stream>>>(attnw, woutt, bout, y);
}

// Round 7
// 290.413 us; speedup vs baseline: 1.0421x; 1.0421x over previous
//
#include <hip/hip_runtime.h>
#include <cstdint>
#include <cstddef>

typedef __bf16 bf16x8 __attribute__((ext_vector_type(8)));
typedef __bf16 bf16x4 __attribute__((ext_vector_type(4)));
typedef float  f32x4  __attribute__((ext_vector_type(4)));

#define MFMA16(a, b, c) __builtin_amdgcn_mfma_f32_16x16x32_bf16((a), (b), (c), 0, 0, 0)

// async global->LDS, 16B per lane. LDS dest MUST be wave_base + lane*16 (contiguous).
#define GLL16(gsrc, ldst)                                                              \
  __builtin_amdgcn_global_load_lds((__attribute__((address_space(1))) void*)(gsrc),    \
                                   (__attribute__((address_space(3))) void*)(ldst),    \
                                   16, 0, 0)

// q pre-scale: 1/sqrt(64) * log2(e), so attention scores land in log2 space
#define QSCALE 0.1803368801111204f

// ---------------------------------------------------------------- conversions

__global__ __launch_bounds__(256)
void cvt_f32_bf16(const float* __restrict__ in, __bf16* __restrict__ out, int n4)
{
    int i = blockIdx.x * 256 + threadIdx.x;
    if (i < n4) {
        float4 v = ((const float4*)in)[i];
        bf16x4 o;
        o[0] = (__bf16)v.x; o[1] = (__bf16)v.y; o[2] = (__bf16)v.z; o[3] = (__bf16)v.w;
        ((bf16x4*)out)[i] = o;
    }
}

// in: fp32 [K][N] row-major -> out: bf16 [N][K] row-major
__global__ __launch_bounds__(256)
void transpose_cvt(const float* __restrict__ in, __bf16* __restrict__ out, int K, int N)
{
    __shared__ __bf16 tile[32][33];
    const int n0 = blockIdx.x * 32, k0 = blockIdx.y * 32;
    const int tx = threadIdx.x, ty = threadIdx.y;
    #pragma unroll
    for (int i = 0; i < 4; ++i)
        tile[ty + i * 8][tx] = (__bf16)in[(size_t)(k0 + ty + i * 8) * N + n0 + tx];
    __syncthreads();
    #pragma unroll
    for (int i = 0; i < 4; ++i)
        out[(size_t)(n0 + ty + i * 8) * K + k0 + tx] = tile[tx][ty + i * 8];
}

// ---------------------------------------------------------------- QKV GEMM
// 128x128 tile + T1 XCD-chunked remap (FETCH 71.8 -> 41.4 MB measured, r4).
// r5: fused V transpose in epilogue (vtrans kernel eliminated).
// r6: 2-phase double-buffered K-loop (T3 minimum recipe, m248): issue next
// tile's GLL16s BEFORE computing current tile, counted vmcnt(4) (never a
// drain mid-loop), raw s_barrier (NOT __syncthreads: that emits vmcnt(0)
// before the barrier and drains the in-flight prefetch). Barrier A (after
// counted vmcnt) publishes cur buf across waves; barrier B (after MFMAs,
// ds_reads already retired by compiler lgkmcnt) protects the next iter's
// stage-WAR into the buffer just read.

union SmemQKV {
    struct { __bf16 As[2][4096]; __bf16 Bs[2][4096]; } g;     // 32 KB dbuf
    __bf16 VtL[2][64][136];                                   // 34 KB
};

__global__ __launch_bounds__(256)
void gemm_qkv(const __bf16* __restrict__ A, const __bf16* __restrict__ Bt,
              const float* __restrict__ bias,
              __bf16* __restrict__ qws, float* __restrict__ kout, float* __restrict__ vout,
              __bf16* __restrict__ kws, __bf16* __restrict__ vwst)
{
    constexpr int K = 1024;
    // XCD-chunked bijective remap (1536 blocks, 1536 % 8 == 0)
    const int d   = blockIdx.y * 24 + blockIdx.x;   // HW dispatch order (x fastest)
    const int xcd = d & 7, loc = d >> 3;            // XCD = d % 8
    const int m0 = (xcd * 8 + (loc & 7)) * 128;     // 8 m-tiles per XCD, hot in L2
    const int n0 = (loc >> 3) * 128;                // n-major sweep within XCD
    const int tid = threadIdx.x;
    const int wave = tid >> 6, lane = tid & 63;
    const int quad = lane >> 4, lr = lane & 15;
    const int wrow = (wave & 1) * 64, wcol = (wave >> 1) * 64;

    __shared__ SmemQKV sm;

    f32x4 acc[4][4];
    #pragma unroll
    for (int mi = 0; mi < 4; ++mi)
      #pragma unroll
      for (int ni = 0; ni < 4; ++ni)
        #pragma unroll
        for (int c = 0; c < 4; ++c) acc[mi][ni][c] = 0.f;

    const int u0 = tid, u1 = tid + 256;
    const int cg0 = ((u0 & 3) ^ ((u0 >> 3) & 3)) * 8;
    const int cg1 = ((u1 & 3) ^ ((u1 >> 3) & 3)) * 8;
    const __bf16* ga0 = A  + (size_t)(m0 + (u0 >> 2)) * K + cg0;
    const __bf16* ga1 = A  + (size_t)(m0 + (u1 >> 2)) * K + cg1;
    const __bf16* gb0 = Bt + (size_t)(n0 + (u0 >> 2)) * K + cg0;
    const __bf16* gb1 = Bt + (size_t)(n0 + (u1 >> 2)) * K + cg1;
    __bf16* la0 = sm.g.As[0] + u0 * 8;
    __bf16* la1 = sm.g.As[0] + u1 * 8;
    __bf16* lb0 = sm.g.Bs[0] + u0 * 8;
    __bf16* lb1 = sm.g.Bs[0] + u1 * 8;

    const int sw = (quad ^ ((lr >> 1) & 3)) * 8;

    // prologue: stage tile 0 into buf 0 (no wait — iter 0 does the counted wait)
    GLL16(ga0, la0);
    GLL16(ga1, la1);
    GLL16(gb0, lb0);
    GLL16(gb1, lb1);

    for (int kt = 0; kt < K; kt += 32) {
        const int buf = (kt >> 5) & 1;
        const bool more = (kt + 32 < K);
        if (more) {
            const int no = (buf ^ 1) * 4096;   // element offset of other buf
            GLL16(ga0 + kt + 32, la0 + no);
            GLL16(ga1 + kt + 32, la1 + no);
            GLL16(gb0 + kt + 32, lb0 + no);
            GLL16(gb1 + kt + 32, lb1 + no);
        }
        if (more) asm volatile("s_waitcnt vmcnt(4)" ::: "memory");
        else      asm volatile("s_waitcnt vmcnt(0)" ::: "memory");
        asm volatile("s_barrier" ::: "memory");          // A: publish cur buf

        bf16x8 af[4], bfv[4];
        #pragma unroll
        for (int mi = 0; mi < 4; ++mi)
            af[mi] = *(const bf16x8*)&sm.g.As[buf][(wrow + mi * 16 + lr) * 32 + sw];
        #pragma unroll
        for (int ni = 0; ni < 4; ++ni)
            bfv[ni] = *(const bf16x8*)&sm.g.Bs[buf][(wcol + ni * 16 + lr) * 32 + sw];
        #pragma unroll
        for (int mi = 0; mi < 4; ++mi)
          #pragma unroll
          for (int ni = 0; ni < 4; ++ni)
            acc[mi][ni] = MFMA16(af[mi], bfv[ni], acc[mi][ni]);

        asm volatile("s_barrier" ::: "memory");          // B: WAR for next stage
    }

    const int sec = n0 >> 10;  // 0=q, 1=k, 2=v (block-uniform: 128 | 1024)
    // (barrier B of the last iter already separates LDS reads from VtL reuse)

    #pragma unroll
    for (int ni = 0; ni < 4; ++ni) {
        const int gn = n0 + wcol + ni * 16 + lr;
        const float bv = bias[gn];
        const int cn = gn & 1023, hh = cn >> 6, dd = cn & 63;
        #pragma unroll
        for (int mi = 0; mi < 4; ++mi) {
            const int gm0 = m0 + wrow + mi * 16 + quad * 4;
            const int b = gm0 >> 11, t0 = gm0 & 2047;
            const size_t tb = ((size_t)b * 16 + hh) * 2048;
            if (sec == 0) {
                #pragma unroll
                for (int r = 0; r < 4; ++r)
                    qws[(tb + t0 + r) * 64 + dd] = (__bf16)((acc[mi][ni][r] + bv) * QSCALE);
            } else if (sec == 1) {
                #pragma unroll
                for (int r = 0; r < 4; ++r) {
                    const float val = acc[mi][ni][r] + bv;
                    kout[(tb + t0 + r) * 64 + dd] = val;
                    kws [(tb + t0 + r) * 64 + dd] = (__bf16)val;
                }
            } else {
                #pragma unroll
                for (int r = 0; r < 4; ++r) {
                    const float val = acc[mi][ni][r] + bv;
                    vout[(tb + t0 + r) * 64 + dd] = val;
                    // sigma-permuted LDS stage for the fused V transpose
                    const int tau = wrow + mi * 16 + quad * 4 + r;     // 0..127
                    const int t64 = tau & 63, blk = tau >> 6;
                    const int p = 4 * (t64 & 15) + (t64 >> 4);
                    sm.VtL[hh & 1][dd][blk * 64 + p] = (__bf16)val;
                }
            }
        }
    }

    if (sec == 2) {
        __syncthreads();
        // write-out: vwst [bh][d][2048], rows of 128 t contiguous
        const int b = m0 >> 11, t_base = m0 & 2047;
        const int hh0 = (n0 & 1023) >> 6;          // even head index of this block
        #pragma unroll
        for (int k = 0; k < 8; ++k) {
            const int e  = (tid + 256 * k) * 8;    // element index
            const int p8 = e & 127;
            const int dd = (e >> 7) & 63;
            const int hl = e >> 13;                // local head 0/1
            bf16x8 v = *(const bf16x8*)&sm.VtL[hl][dd][p8];
            const int bh = b * 16 + hh0 + hl;
            *(bf16x8*)&vwst[((size_t)bh * 64 + dd) * 2048 + t_base + p8] = v;
        }
    }
}

// ---------------------------------------------------------------- out-proj GEMM
// 128x128 tile, grid (8,64) = 512 blocks; natural XCD affinity (d%8 = x = n-tile,
// one 256 KB B panel L2-hot per XCD). r6: same 2-phase dbuf K-loop as gemm_qkv.

__global__ __launch_bounds__(256)
void gemm_out(const __bf16* __restrict__ A, const __bf16* __restrict__ Bt,
              const float* __restrict__ bias, float* __restrict__ y)
{
    constexpr int K = 1024;
    const int m0 = blockIdx.y * 128, n0 = blockIdx.x * 128;
    const int tid = threadIdx.x;
    const int wave = tid >> 6, lane = tid & 63;
    const int quad = lane >> 4, lr = lane & 15;
    const int wrow = (wave & 1) * 64, wcol = (wave >> 1) * 64;

    __shared__ __bf16 As[2][4096];
    __shared__ __bf16 Bs[2][4096];

    f32x4 acc[4][4];
    #pragma unroll
    for (int mi = 0; mi < 4; ++mi)
      #pragma unroll
      for (int ni = 0; ni < 4; ++ni)
        #pragma unroll
        for (int c = 0; c < 4; ++c) acc[mi][ni][c] = 0.f;

    const int u0 = tid, u1 = tid + 256;
    const int cg0 = ((u0 & 3) ^ ((u0 >> 3) & 3)) * 8;
    const int cg1 = ((u1 & 3) ^ ((u1 >> 3) & 3)) * 8;
    const __bf16* ga0 = A  + (size_t)(m0 + (u0 >> 2)) * K + cg0;
    const __bf16* ga1 = A  + (size_t)(m0 + (u1 >> 2)) * K + cg1;
    const __bf16* gb0 = Bt + (size_t)(n0 + (u0 >> 2)) * K + cg0;
    const __bf16* gb1 = Bt + (size_t)(n0 + (u1 >> 2)) * K + cg1;
    __bf16* la0 = As[0] + u0 * 8;
    __bf16* la1 = As[0] + u1 * 8;
    __bf16* lb0 = Bs[0] + u0 * 8;
    __bf16* lb1 = Bs[0] + u1 * 8;

    const int sw = (quad ^ ((lr >> 1) & 3)) * 8;

    GLL16(ga0, la0);
    GLL16(ga1, la1);
    GLL16(gb0, lb0);
    GLL16(gb1, lb1);

    for (int kt = 0; kt < K; kt += 32) {
        const int buf = (kt >> 5) & 1;
        const bool more = (kt + 32 < K);
        if (more) {
            const int no = (buf ^ 1) * 4096;
            GLL16(ga0 + kt + 32, la0 + no);
            GLL16(ga1 + kt + 32, la1 + no);
            GLL16(gb0 + kt + 32, lb0 + no);
            GLL16(gb1 + kt + 32, lb1 + no);
        }
        if (more) asm volatile("s_waitcnt vmcnt(4)" ::: "memory");
        else      asm volatile("s_waitcnt vmcnt(0)" ::: "memory");
        asm volatile("s_barrier" ::: "memory");

        bf16x8 af[4], bfv[4];
        #pragma unroll
        for (int mi = 0; mi < 4; ++mi)
            af[mi] = *(const bf16x8*)&As[buf][(wrow + mi * 16 + lr) * 32 + sw];
        #pragma unroll
        for (int ni = 0; ni < 4; ++ni)
            bfv[ni] = *(const bf16x8*)&Bs[buf][(wcol + ni * 16 + lr) * 32 + sw];
        #pragma unroll
        for (int mi = 0; mi < 4; ++mi)
          #pragma unroll
          for (int ni = 0; ni < 4; ++ni)
            acc[mi][ni] = MFMA16(af[mi], bfv[ni], acc[mi][ni]);

        asm volatile("s_barrier" ::: "memory");
    }

    #pragma unroll
    for (int ni = 0; ni < 4; ++ni) {
        const int gn = n0 + wcol + ni * 16 + lr;
        const float bv = bias[gn];
        #pragma unroll
        for (int mi = 0; mi < 4; ++mi) {
            #pragma unroll
            for (int r = 0; r < 4; ++r) {
                const int gm = m0 + wrow + mi * 16 + quad * 4 + r;
                y[(size_t)gm * 1024 + gn] = acc[mi][ni][r] + bv;
            }
        }
    }
}

// ---------------------------------------------------------------- flash attention
// Grid (bh, pair): all 8 pair-blocks of a bh land on one XCD (linear id % 8 = bh % 8).
// Two serialized phases (q-tiles {x,15-x}), 34 tile-iters per block. Fixed-shift
// softmax: sacc init = -12, p = exp2(s-12), exact after final 1/l (no running max).
// 3-buffer KV, 2-deep prefetch, ONE barrier per iter (prefetch targets buf+2).
// r5: s_setprio(1) around MFMA packs (T5). Unchanged in r6.

__global__ __launch_bounds__(256, 2)
void attn_fused(const __bf16* __restrict__ qws, const __bf16* __restrict__ kws,
                const __bf16* __restrict__ vwst, __bf16* __restrict__ attnws)
{
    const int bh = blockIdx.x;          // b*16 + h
    const int tid = threadIdx.x;
    const int wave = tid >> 6, lane = tid & 63;
    const int quad = lane >> 4, lr = lane & 15;

    const int jqp[2] = { (int)blockIdx.y, 15 - (int)blockIdx.y };
    const int ntp[2] = { 2 * (jqp[0] + 1), 2 * (jqp[1] + 1) };
    const int nt0 = ntp[0];
    const int ntot = 34;

    __shared__ __bf16 Ks [3][2][64][32];   // [buf][s][kv][d32]   swizzled cols
    __shared__ __bf16 Vts[3][2][64][32];   // [buf][s][d][p32]    swizzled cols
    __shared__ __bf16 Ps [4][32][72];      // per-wave P, c_store = 4*lr+ni order

    // staging addresses
    const int srow = tid >> 2;
    const int scg  = ((tid & 3) ^ ((tid >> 3) & 3)) * 8;
    const __bf16* kb = kws  + ((size_t)bh * 2048 + srow) * 64 + scg;
    const __bf16* vb = vwst + ((size_t)bh * 64 + srow) * 2048 + scg;
    char* lk = (char*)Ks  + tid * 16;   // + buf*8192 (+4096 for s1)
    char* lv = (char*)Vts + tid * 16;

    const int sw = (quad ^ ((lr >> 1) & 3)) * 8;

    bf16x8 ones;
    #pragma unroll
    for (int j = 0; j < 8; ++j) ones[j] = (__bf16)1.0f;

    // Q fragments for BOTH phases up-front (keeps vmcnt FIFO discipline clean)
    bf16x8 aq[2][2][2];
    #pragma unroll
    for (int h = 0; h < 2; ++h)
      #pragma unroll
      for (int mi = 0; mi < 2; ++mi) {
        const __bf16* qb = qws + ((size_t)bh * 2048 + jqp[h] * 128 + wave * 32 + mi * 16 + lr) * 64 + quad * 8;
        aq[h][mi][0] = *(const bf16x8*)qb;
        aq[h][mi][1] = *(const bf16x8*)(qb + 32);
      }

#define PREFETCH(j, buf)                                                \
    do {                                                                \
        GLL16(kb + (size_t)(j) * 4096,      lk + (buf) * 8192);         \
        GLL16(kb + (size_t)(j) * 4096 + 32, lk + (buf) * 8192 + 4096);  \
        GLL16(vb + (j) * 64,                lv + (buf) * 8192);         \
        GLL16(vb + (j) * 64 + 32,           lv + (buf) * 8192 + 4096);  \
    } while (0)

    // prologue: tiles 0 and 1 (phase-0 always has >= 2 tiles)
    PREFETCH(0, 0);
    PREFETCH(1, 1);

    bf16x4 oreg[2][2][4];   // [h][mi][n], r packed in vector lanes

    int pos = 0;
    for (int h = 0; h < 2; ++h) {
        const int jq = jqp[h];
        const int NT = ntp[h];

        f32x4 o_acc[2][4], l_acc[2];
        #pragma unroll
        for (int mi = 0; mi < 2; ++mi) {
            #pragma unroll
            for (int r = 0; r < 4; ++r) l_acc[mi][r] = 0.f;
            #pragma unroll
            for (int n = 0; n < 4; ++n)
                #pragma unroll
                for (int r = 0; r < 4; ++r) o_acc[mi][n][r] = 0.f;
        }

        for (int jt = 0; jt < NT; ++jt, ++pos) {
            const int cur = pos % 3;
            // tile `pos` was requested 2 iters ago; tile pos+1 is 1 deep in flight
            if (pos + 1 < ntot) {
                asm volatile("s_waitcnt vmcnt(4)" ::: "memory");
            } else {
                asm volatile("s_waitcnt vmcnt(0)" ::: "memory");
            }
            asm volatile("s_waitcnt lgkmcnt(0)" ::: "memory");
            asm volatile("s_barrier" ::: "memory");
            if (pos + 2 < ntot) {
                const int p2 = pos + 2;
                const int nj = (p2 < nt0) ? p2 : p2 - nt0;
                PREFETCH(nj, p2 % 3);
            }

            const bool lastTile = (jt == NT - 1);
            if (!(lastTile && wave < 2)) {
                // S = Q K^T, C initialized to -12 (fixed softmax shift, free)
                bf16x8 bk[4][2];
                #pragma unroll
                for (int ni = 0; ni < 4; ++ni) {
                    bk[ni][0] = *(const bf16x8*)&Ks[cur][0][ni * 16 + lr][sw];
                    bk[ni][1] = *(const bf16x8*)&Ks[cur][1][ni * 16 + lr][sw];
                }
                f32x4 sacc[2][4];
                #pragma unroll
                for (int mi = 0; mi < 2; ++mi)
                  #pragma unroll
                  for (int ni = 0; ni < 4; ++ni)
                    #pragma unroll
                    for (int c = 0; c < 4; ++c) sacc[mi][ni][c] = -12.f;
                __builtin_amdgcn_s_setprio(1);
                #pragma unroll
                for (int ni = 0; ni < 4; ++ni)
                  #pragma unroll
                  for (int mi = 0; mi < 2; ++mi) {
                    sacc[mi][ni] = MFMA16(aq[h][mi][0], bk[ni][0], sacc[mi][ni]);
                    sacc[mi][ni] = MFMA16(aq[h][mi][1], bk[ni][1], sacc[mi][ni]);
                  }
                __builtin_amdgcn_s_setprio(0);

                // causal mask: only waves whose rows straddle this tile
                const bool needMask = (jt == NT - 2 && wave < 2) || (lastTile && wave >= 2);
                if (needMask) {
                    const int c0 = jt * 64 + lr;
                    #pragma unroll
                    for (int mi = 0; mi < 2; ++mi) {
                        const int t0 = jq * 128 + wave * 32 + mi * 16 + quad * 4;
                        #pragma unroll
                        for (int ni = 0; ni < 4; ++ni)
                          #pragma unroll
                          for (int r = 0; r < 4; ++r)
                            if (c0 + ni * 16 > t0 + r) sacc[mi][ni][r] = -1e30f;
                    }
                }

                // p = exp2(s - 12); packed b64 store (no max, no alpha)
                #pragma unroll
                for (int mi = 0; mi < 2; ++mi)
                  #pragma unroll
                  for (int r = 0; r < 4; ++r) {
                    bf16x4 pp;
                    #pragma unroll
                    for (int ni = 0; ni < 4; ++ni)
                        pp[ni] = (__bf16)__builtin_amdgcn_exp2f(sacc[mi][ni][r]);
                    *(bf16x4*)&Ps[wave][mi * 16 + quad * 4 + r][4 * lr] = pp;
                  }

                // Ps is wave-private: drain own LDS writes, no barrier
                asm volatile("s_waitcnt lgkmcnt(0)" ::: "memory");

                // O += P V ; l += P . 1   (V rows sigma-permuted to match P)
                bf16x8 bv[4][2];
                #pragma unroll
                for (int n = 0; n < 4; ++n) {
                    bv[n][0] = *(const bf16x8*)&Vts[cur][0][n * 16 + lr][sw];
                    bv[n][1] = *(const bf16x8*)&Vts[cur][1][n * 16 + lr][sw];
                }
                __builtin_amdgcn_s_setprio(1);
                #pragma unroll
                for (int mi = 0; mi < 2; ++mi) {
                    bf16x8 ap0 = *(const bf16x8*)&Ps[wave][mi * 16 + lr][quad * 8];
                    bf16x8 ap1 = *(const bf16x8*)&Ps[wave][mi * 16 + lr][32 + quad * 8];
                    l_acc[mi] = MFMA16(ap0, ones, l_acc[mi]);
                    l_acc[mi] = MFMA16(ap1, ones, l_acc[mi]);
                    #pragma unroll
                    for (int n = 0; n < 4; ++n) {
                        o_acc[mi][n] = MFMA16(ap0, bv[n][0], o_acc[mi][n]);
                        o_acc[mi][n] = MFMA16(ap1, bv[n][1], o_acc[mi][n]);
                    }
                }
                __builtin_amdgcn_s_setprio(0);
            }
        }

        // normalize into registers (stores deferred to kernel end)
        #pragma unroll
        for (int mi = 0; mi < 2; ++mi)
          #pragma unroll
          for (int r = 0; r < 4; ++r) {
            const float inv = 1.f / l_acc[mi][r];
            #pragma unroll
            for (int n = 0; n < 4; ++n)
                oreg[h][mi][n][r] = (__bf16)(o_acc[mi][n][r] * inv);
          }
    }

    // epilogue: store both phases (bf16, [B,T,NH*HD] for the out-proj GEMM)
    const int b = bh >> 4, h16 = bh & 15;
    #pragma unroll
    for (int h = 0; h < 2; ++h)
      #pragma unroll
      for (int mi = 0; mi < 2; ++mi)
        #pragma unroll
        for (int r = 0; r < 4; ++r) {
            const int t = jqp[h] * 128 + wave * 32 + mi * 16 + quad * 4 + r;
            #pragma unroll
            for (int n = 0; n < 4; ++n)
                attnws[(((size_t)b * 2048 + t) * 16 + h16) * 64 + n * 16 + lr] =
                    oreg[h][mi][n][r];
        }
#undef PREFETCH
}

// ---------------------------------------------------------------- launcher

extern "C" void kernel_launch(void* const* d_in, const int* in_sizes, int n_in,
                              void* d_out, int out_size, void* d_ws, size_t ws_size,
                              hipStream_t stream)
{
    (void)in_sizes; (void)n_in; (void)out_size; (void)ws_size;

    const float* x    = (const float*)d_in[0];
    const float* Wqkv = (const float*)d_in[1];
    const float* bqkv = (const float*)d_in[2];
    const float* Wout = (const float*)d_in[3];
    const float* bout = (const float*)d_in[4];

    float* y    = (float*)d_out;          // [4,2048,1024]
    float* kout = y + 8388608;            // [4,16,2048,64]
    float* vout = kout + 8388608;         // [4,16,2048,64]

    char* ws = (char*)d_ws;
    __bf16* xb    = (__bf16*)(ws);                       // 16 MB  [8192,1024]
    __bf16* wqkvt = (__bf16*)(ws + (16u << 20));         //  6 MB  [3072,1024]
    __bf16* woutt = (__bf16*)(ws + (22u << 20));         //  2 MB  [1024,1024]
    __bf16* qws   = (__bf16*)(ws + (24u << 20));         // 16 MB  [64,2048,64]  (pre-scaled)
    __bf16* kws   = (__bf16*)(ws + (40u << 20));         // 16 MB  [64,2048,64]
    __bf16* vwst  = (__bf16*)(ws + (56u << 20));         // 16 MB  [64,64,2048]  (sigma-permuted)
    __bf16* attnw = (__bf16*)(ws + (72u << 20));         // 16 MB  [8192,1024]

    cvt_f32_bf16<<<8192, 256, 0, stream>>>(x, xb, 2097152);
    transpose_cvt<<<dim3(96, 32), dim3(32, 8), 0, stream>>>(Wqkv, wqkvt, 1024, 3072);
    transpose_cvt<<<dim3(32, 32), dim3(32, 8), 0, stream>>>(Wout, woutt, 1024, 1024);
    gemm_qkv<<<dim3(24, 64), 256, 0, stream>>>(xb, wqkvt, bqkv, qws, kout, vout, kws, vwst);
    attn_fused<<<dim3(64, 8), 256, 0, stream>>>(qws, kws, vwst, attnw);
    gemm_out<<<dim3(8, 64), 256, 0, stream>>>(attnw, woutt, bout, y);
}